// Round 4
// baseline (575.988 us; speedup 1.0000x reference)
//
#include <hip/hip_runtime.h>
#include <hip/hip_bf16.h>
#include <stdint.h>

typedef unsigned short u16;
typedef __attribute__((ext_vector_type(4))) unsigned int u32x4;
typedef __attribute__((ext_vector_type(8))) __bf16 bfx8;
typedef __attribute__((ext_vector_type(4))) float f32x4;

#define PI_F 3.14159265358979323846f

__device__ __forceinline__ float bf2f(u16 u) {
    unsigned v = ((unsigned)u) << 16; float f; __builtin_memcpy(&f, &v, 4); return f;
}
__device__ __forceinline__ u16 f2bf(float f) {
    unsigned u; __builtin_memcpy(&u, &f, 4);
    unsigned r = (u + 0x7fffu + ((u >> 16) & 1u)) >> 16; return (u16)r;
}

// global -> LDS direct DMA, 16B per lane. LDS dest must be lane-linear.
__device__ __forceinline__ void glds16(const u16* g, const u16* l) {
    __builtin_amdgcn_global_load_lds(
        (const __attribute__((address_space(1))) unsigned int*)(unsigned long long)g,
        (__attribute__((address_space(3))) unsigned int*)(unsigned int)(unsigned long long)l,
        16, 0, 0);
}

// ---------------------------------------------------------------------------
// Generic tiled transpose + f32->bf16 convert:  out[c][r] = in[r][c], batched.
// ---------------------------------------------------------------------------
__global__ __launch_bounds__(256)
void tconv_kernel(const float* __restrict__ in, u16* __restrict__ out,
                  int R, int C, long inBatch, long outBatch)
{
    __shared__ float tile[64][65];
    const int tx = threadIdx.x & 63;
    const int ty = threadIdx.x >> 6;
    const int bc = blockIdx.x * 64;
    const int br = blockIdx.y * 64;
    const float* ip = in + (long)blockIdx.z * inBatch;
    u16* op = out + (long)blockIdx.z * outBatch;

    #pragma unroll
    for (int rr = ty; rr < 64; rr += 4) {
        int r = br + rr, c = bc + tx;
        tile[rr][tx] = (r < R && c < C) ? ip[(long)r * C + c] : 0.f;
    }
    __syncthreads();
    #pragma unroll
    for (int rr = ty; rr < 64; rr += 4) {
        int oc = bc + rr;
        int orr = br + tx;
        if (oc < C && orr < R)
            op[(long)oc * R + orr] = f2bf(tile[tx][rr]);
    }
}

// ---------------------------------------------------------------------------
// LayerNorm (+ optional rank-1 q/k projections + tanh/cos/sin).
// ---------------------------------------------------------------------------
template<bool DO_QK>
__global__ __launch_bounds__(256)
void ln_kernel(const float* __restrict__ X, const float* __restrict__ w,
               const float* __restrict__ b, u16* __restrict__ Ybf,
               const float* __restrict__ WQ, const float* __restrict__ WK,
               float* __restrict__ cqA, float* __restrict__ sqA,
               float* __restrict__ ckA, float* __restrict__ skA)
{
    __shared__ float yrow[1024];
    __shared__ float wsum[4], wsq[4];
    const int row = blockIdx.x;
    const int tid = threadIdx.x;
    const int lane = tid & 63;
    const int wv = tid >> 6;

    const float4 xv = ((const float4*)(X + (long)row * 1024))[tid];
    float s  = xv.x + xv.y + xv.z + xv.w;
    float sq = xv.x*xv.x + xv.y*xv.y + xv.z*xv.z + xv.w*xv.w;
    #pragma unroll
    for (int off = 32; off; off >>= 1) {
        s  += __shfl_down(s, off);
        sq += __shfl_down(sq, off);
    }
    if (lane == 0) { wsum[wv] = s; wsq[wv] = sq; }
    __syncthreads();
    const float ts = wsum[0] + wsum[1] + wsum[2] + wsum[3];
    const float tq = wsq[0] + wsq[1] + wsq[2] + wsq[3];
    const float mean = ts * (1.f / 1024.f);
    const float var  = tq * (1.f / 1024.f) - mean * mean;
    const float rstd = rsqrtf(var + 1e-5f);

    const float4 wv4 = ((const float4*)w)[tid];
    const float4 bv4 = ((const float4*)b)[tid];
    const float y0 = (xv.x - mean) * rstd * wv4.x + bv4.x;
    const float y1 = (xv.y - mean) * rstd * wv4.y + bv4.y;
    const float y2 = (xv.z - mean) * rstd * wv4.z + bv4.z;
    const float y3 = (xv.w - mean) * rstd * wv4.w + bv4.w;

    uint2 p;
    p.x = (unsigned)f2bf(y0) | ((unsigned)f2bf(y1) << 16);
    p.y = (unsigned)f2bf(y2) | ((unsigned)f2bf(y3) << 16);
    ((uint2*)(Ybf + (long)row * 1024))[tid] = p;

    if (DO_QK) {
        yrow[tid*4+0] = y0; yrow[tid*4+1] = y1;
        yrow[tid*4+2] = y2; yrow[tid*4+3] = y3;
        __syncthreads();
        #pragma unroll
        for (int i = 0; i < 4; ++i) {
            const int h = wv * 4 + i;
            const float* wqp = WQ + (long)h * 1024;
            const float* wkp = WK + (long)h * 1024;
            float dq = 0.f, dk = 0.f;
            #pragma unroll
            for (int j = 0; j < 16; ++j) {
                const float yv = yrow[lane + 64*j];
                dq = fmaf(yv, wqp[lane + 64*j], dq);
                dk = fmaf(yv, wkp[lane + 64*j], dk);
            }
            #pragma unroll
            for (int off = 32; off; off >>= 1) {
                dq += __shfl_down(dq, off);
                dk += __shfl_down(dk, off);
            }
            if (lane == 0) {
                const float aq = tanhf(dq) * (PI_F * 0.25f);
                const float ak = tanhf(dk) * (PI_F * 0.25f);
                float sv, cv;
                const long o = (long)h * 8192 + row;
                __sincosf(aq, &sv, &cv); cqA[o] = cv; sqA[o] = sv;
                __sincosf(ak, &sv, &cv); ckA[o] = cv; skA[o] = sv;
            }
        }
    }
}

// ---------------------------------------------------------------------------
// Fused cumsum scan + heads: one wave per (b, head).
// ---------------------------------------------------------------------------
__global__ __launch_bounds__(64)
void scan_kernel(const u16* __restrict__ V,
                 const float* __restrict__ cqA, const float* __restrict__ sqA,
                 const float* __restrict__ ckA, const float* __restrict__ skA,
                 u16* __restrict__ H)
{
    __shared__ u16 vt[64][64];
    __shared__ float lck[64], lsk[64], lrc[64], lrs[64];
    const int b = blockIdx.x >> 4;
    const int h = blockIdx.x & 15;
    const int lane = threadIdx.x;
    const long rowbase = (long)b * 2048;
    const long colbase = (long)h * 64;
    const long qbase = (long)h * 8192 + rowbase;

    float csum = 0.f, ssum = 0.f;
    float carry_c = 0.f, carry_s = 0.f;

    for (int ch = 0; ch < 32; ++ch) {
        const int t0 = ch * 64;
        __syncthreads();
        #pragma unroll
        for (int i = 0; i < 8; ++i) {
            const int tt = i * 8 + (lane >> 3);
            const int c0 = (lane & 7) * 8;
            *(u32x4*)&vt[tt][c0] =
                *(const u32x4*)(V + (rowbase + t0 + tt) * 1024 + colbase + c0);
        }
        {
            const float ck = ckA[qbase + t0 + lane];
            const float sk = skA[qbase + t0 + lane];
            const float cq = cqA[qbase + t0 + lane];
            const float sq = sqA[qbase + t0 + lane];
            float c = ck, sscan = sk;
            #pragma unroll
            for (int off = 1; off < 64; off <<= 1) {
                const float oc = __shfl_up(c, off);
                const float os = __shfl_up(sscan, off);
                if (lane >= off) { c += oc; sscan += os; }
            }
            const float cK = carry_c + c;
            const float sK = carry_s + sscan;
            carry_c += __shfl(c, 63);
            carry_s += __shfl(sscan, 63);
            const float denom = cq * cK + sq * sK + 1e-6f;
            lck[lane] = ck; lsk[lane] = sk;
            lrc[lane] = cq / denom; lrs[lane] = sq / denom;
        }
        __syncthreads();
        u16* outp = H + (rowbase + t0) * 1024 + colbase + lane;
        #pragma unroll 8
        for (int tt = 0; tt < 64; ++tt) {
            const float v = bf2f(vt[tt][lane]);
            csum = fmaf(lck[tt], v, csum);
            ssum = fmaf(lsk[tt], v, ssum);
            const float hv = lrc[tt] * csum + lrs[tt] * ssum;
            outp[(long)tt * 1024] = f2bf(hv);
        }
    }
}

// ---------------------------------------------------------------------------
// 256x256 8-wave (2M x 4N) bf16 MFMA GEMM, BK=64, 2 LDS tile-buffers.
// 4 phases per K-tile: {ds_read frags | glds stage t+1 | raw s_barrier |
// lgkmcnt(0) | setprio(1) 16 MFMA setprio(0) | raw s_barrier}.
// One vmcnt(0) per K-tile at the boundary; stage issued 3 phases earlier so
// the drain is cheap. ALL in-loop barriers are raw asm (no builtin) so the
// compiler cannot insert vmcnt(0) drains for the in-flight global_load_lds.
// Chunk-rotation swizzle: row r's logical 16B-chunk c lives at phys chunk
// (c + r%8)%8 -> conflict-free ds_read_b128 (verified 0 in round 2/3).
// EPI: 0 bf16 store; 1 f32 +res; 2 bf16 gelu(+bias); 3 f32 +res+bias.
// ---------------------------------------------------------------------------
template<int EPI>
__global__ __launch_bounds__(512, 2)
void gemm256(const u16* __restrict__ A, const u16* __restrict__ B,
             void* __restrict__ Cout, const float* __restrict__ res,
             const float* __restrict__ bias, int M, int N, int K, int nx)
{
    __shared__ u16 As[2 * 256 * 64];   // 64 KB
    __shared__ u16 Bs[2 * 256 * 64];   // 64 KB
    const int tid  = threadIdx.x;
    const int lane = tid & 63;
    const int wave = tid >> 6;
    const int wr = wave >> 2;          // 0..1  (M half, 128 rows)
    const int wc = wave & 3;           // 0..3  (N quarter, 64 cols)

    // XCD-colocating block swizzle
    const int L = blockIdx.x;
    const int xcd = L & 7;
    const int qq = L >> 3;
    const int bx = qq % nx;
    const int by = (qq / nx) * 8 + xcd;
    const int brow = by * 256;
    const int bcol = bx * 256;

    // stage addressing: thread t covers row srow8 (0..63) chunk ch of each
    // 64-row quarter; source chunk = logical chunk for phys slot ch.
    const int srow8 = tid >> 3;
    const int chp   = tid & 7;
    const int clog  = (chp - (srow8 & 7)) & 7;
    const u16* Ag = A + (long)(brow + srow8) * K + clog * 8;
    const u16* Bg = B + (long)(bcol + srow8) * K + clog * 8;
    const long rowK64 = (long)64 * K;

    // fragment lane offsets (bytes within a 64-row quarter... full row=128B)
    const int rr = lane & 15;
    const int kq = lane >> 4;
    const int lo0 = rr * 128 + ((kq + (rr & 7)) & 7) * 16;       // k-half 0
    const int lo1 = rr * 128 + ((kq + 4 + (rr & 7)) & 7) * 16;   // k-half 1
    const char* Ac = (const char*)As;
    const char* Bc = (const char*)Bs;
    const int aoff = wr * 16384;                       // wave's A half
    const int boff = (wc >> 1) * 16384 + (wc & 1) * 8192;

    f32x4 acc[8][4];
    #pragma unroll
    for (int i = 0; i < 8; ++i)
        #pragma unroll
        for (int j = 0; j < 4; ++j) acc[i][j] = (f32x4){0.f, 0.f, 0.f, 0.f};

    const int NT = K >> 6;

    // prologue: stage tile 0 into buf 0
    #pragma unroll
    for (int q4 = 0; q4 < 4; ++q4) {
        glds16(Ag + (long)q4 * rowK64, &As[q4 * 4096 + tid * 8]);
        glds16(Bg + (long)q4 * rowK64, &Bs[q4 * 4096 + tid * 8]);
    }
    asm volatile("s_waitcnt vmcnt(0)" ::: "memory");
    asm volatile("s_barrier" ::: "memory");

    for (int t = 0; t < NT; ++t) {
        const int p  = t & 1;
        const int pn = p ^ 1;
        const long kofn = (long)((t + 1 < NT) ? (t + 1) : 0) * 64;
        const char* Ap = Ac + p * 32768;
        const char* Bp = Bc + p * 32768;

        bfx8 bA[8], bB0[4], bB1[4];

        // ===== phase 0: frags A(mh0)+B(nh0); stage A(t+1)
        #pragma unroll
        for (int m = 0; m < 4; ++m) {
            bA[m*2+0] = *(const bfx8*)(Ap + aoff + m * 2048 + lo0);
            bA[m*2+1] = *(const bfx8*)(Ap + aoff + m * 2048 + lo1);
        }
        #pragma unroll
        for (int n = 0; n < 2; ++n) {
            bB0[n*2+0] = *(const bfx8*)(Bp + boff + n * 2048 + lo0);
            bB0[n*2+1] = *(const bfx8*)(Bp + boff + n * 2048 + lo1);
        }
        #pragma unroll
        for (int q4 = 0; q4 < 4; ++q4)
            glds16(Ag + kofn + (long)q4 * rowK64,
                   &As[pn * 16384 + q4 * 4096 + tid * 8]);
        asm volatile("s_barrier" ::: "memory");
        asm volatile("s_waitcnt lgkmcnt(0)" ::: "memory");
        __builtin_amdgcn_sched_barrier(0);
        __builtin_amdgcn_s_setprio(1);
        #pragma unroll
        for (int m = 0; m < 4; ++m)
            #pragma unroll
            for (int n = 0; n < 2; ++n) {
                acc[m][n] = __builtin_amdgcn_mfma_f32_16x16x32_bf16(bA[m*2+0], bB0[n*2+0], acc[m][n], 0, 0, 0);
                acc[m][n] = __builtin_amdgcn_mfma_f32_16x16x32_bf16(bA[m*2+1], bB0[n*2+1], acc[m][n], 0, 0, 0);
            }
        __builtin_amdgcn_s_setprio(0);
        __builtin_amdgcn_sched_barrier(0);
        asm volatile("s_barrier" ::: "memory");

        // ===== phase 1: frags B(nh1); stage B(t+1)
        #pragma unroll
        for (int n = 0; n < 2; ++n) {
            bB1[n*2+0] = *(const bfx8*)(Bp + boff + (2 + n) * 2048 + lo0);
            bB1[n*2+1] = *(const bfx8*)(Bp + boff + (2 + n) * 2048 + lo1);
        }
        #pragma unroll
        for (int q4 = 0; q4 < 4; ++q4)
            glds16(Bg + kofn + (long)q4 * rowK64,
                   &Bs[pn * 16384 + q4 * 4096 + tid * 8]);
        asm volatile("s_barrier" ::: "memory");
        asm volatile("s_waitcnt lgkmcnt(0)" ::: "memory");
        __builtin_amdgcn_sched_barrier(0);
        __builtin_amdgcn_s_setprio(1);
        #pragma unroll
        for (int m = 0; m < 4; ++m)
            #pragma unroll
            for (int n = 0; n < 2; ++n) {
                acc[m][2+n] = __builtin_amdgcn_mfma_f32_16x16x32_bf16(bA[m*2+0], bB1[n*2+0], acc[m][2+n], 0, 0, 0);
                acc[m][2+n] = __builtin_amdgcn_mfma_f32_16x16x32_bf16(bA[m*2+1], bB1[n*2+1], acc[m][2+n], 0, 0, 0);
            }
        __builtin_amdgcn_s_setprio(0);
        __builtin_amdgcn_sched_barrier(0);
        asm volatile("s_barrier" ::: "memory");

        // ===== phase 2: frags A(mh1); no stage
        #pragma unroll
        for (int m = 0; m < 4; ++m) {
            bA[m*2+0] = *(const bfx8*)(Ap + aoff + 8192 + m * 2048 + lo0);
            bA[m*2+1] = *(const bfx8*)(Ap + aoff + 8192 + m * 2048 + lo1);
        }
        asm volatile("s_barrier" ::: "memory");
        asm volatile("s_waitcnt lgkmcnt(0)" ::: "memory");
        __builtin_amdgcn_sched_barrier(0);
        __builtin_amdgcn_s_setprio(1);
        #pragma unroll
        for (int m = 0; m < 4; ++m)
            #pragma unroll
            for (int n = 0; n < 2; ++n) {
                acc[4+m][2+n] = __builtin_amdgcn_mfma_f32_16x16x32_bf16(bA[m*2+0], bB1[n*2+0], acc[4+m][2+n], 0, 0, 0);
                acc[4+m][2+n] = __builtin_amdgcn_mfma_f32_16x16x32_bf16(bA[m*2+1], bB1[n*2+1], acc[4+m][2+n], 0, 0, 0);
            }
        __builtin_amdgcn_s_setprio(0);
        __builtin_amdgcn_sched_barrier(0);
        asm volatile("s_barrier" ::: "memory");

        // ===== phase 3: mh1 x nh0 (bB0 retained); boundary drain
        __builtin_amdgcn_s_setprio(1);
        #pragma unroll
        for (int m = 0; m < 4; ++m)
            #pragma unroll
            for (int n = 0; n < 2; ++n) {
                acc[4+m][n] = __builtin_amdgcn_mfma_f32_16x16x32_bf16(bA[m*2+0], bB0[n*2+0], acc[4+m][n], 0, 0, 0);
                acc[4+m][n] = __builtin_amdgcn_mfma_f32_16x16x32_bf16(bA[m*2+1], bB0[n*2+1], acc[4+m][n], 0, 0, 0);
            }
        __builtin_amdgcn_s_setprio(0);
        __builtin_amdgcn_sched_barrier(0);
        asm volatile("s_waitcnt vmcnt(0)" ::: "memory");
        asm volatile("s_barrier" ::: "memory");
    }

    // epilogue
    const int crow0 = brow + wr * 128 + (lane >> 4) * 4;
    const int ccol0 = bcol + wc * 64 + rr;
    #pragma unroll
    for (int mi = 0; mi < 8; ++mi) {
        #pragma unroll
        for (int ni = 0; ni < 4; ++ni) {
            const int col = ccol0 + ni * 16;
            #pragma unroll
            for (int r = 0; r < 4; ++r) {
                const int row = crow0 + mi * 16 + r;
                const long idx = (long)row * N + col;
                const float v = acc[mi][ni][r];
                if (EPI == 0) {
                    ((u16*)Cout)[idx] = f2bf(v);
                } else if (EPI == 1) {
                    ((float*)Cout)[idx] = v + res[idx];
                } else if (EPI == 2) {
                    const float hh = v + bias[col];
                    const float z = 0.7978845608028654f * (hh + 0.044715f * hh * hh * hh);
                    const float e = __expf(2.f * z);
                    const float th = 1.f - 2.f / (e + 1.f);
                    ((u16*)Cout)[idx] = f2bf(0.5f * hh * (1.f + th));
                } else {
                    ((float*)Cout)[idx] = v + res[idx] + bias[col];
                }
            }
        }
    }
}

// ---------------------------------------------------------------------------
extern "C" void kernel_launch(void* const* d_in, const int* in_sizes, int n_in,
                              void* d_out, int out_size, void* d_ws, size_t ws_size,
                              hipStream_t stream)
{
    (void)in_sizes; (void)n_in; (void)out_size; (void)ws_size;
    const float* x    = (const float*)d_in[0];
    const float* WQ   = (const float*)d_in[1];
    const float* WK   = (const float*)d_in[2];
    const float* WV   = (const float*)d_in[3];
    const float* WO   = (const float*)d_in[4];
    const float* ln1w = (const float*)d_in[5];
    const float* ln1b = (const float*)d_in[6];
    const float* ln2w = (const float*)d_in[7];
    const float* ln2b = (const float*)d_in[8];
    const float* W1   = (const float*)d_in[9];
    const float* b1   = (const float*)d_in[10];
    const float* W2   = (const float*)d_in[11];
    const float* b2   = (const float*)d_in[12];
    float* out = (float*)d_out;

    char* ws = (char*)d_ws;
    u16*   Ybf  = (u16*)(ws + 0);                    // 16 MB (reused as y2)
    u16*   Vbf  = (u16*)(ws + 16777216);             // 16 MB
    u16*   Hbf  = (u16*)(ws + 33554432);             // 16 MB
    float* X2   = (float*)(ws + 50331648);           // 32 MB
    u16*   H1   = (u16*)(ws + 83886080);             // 64 MB
    u16*   WVT  = (u16*)(ws + 150994944);            //  2 MB
    u16*   WOT  = (u16*)(ws + 153092096);            //  2 MB
    u16*   W1T  = (u16*)(ws + 155189248);            //  8 MB
    u16*   W2T  = (u16*)(ws + 163577856);            //  8 MB
    float* CQ   = (float*)(ws + 171966464);
    float* SQ   = (float*)(ws + 172490752);
    float* CK   = (float*)(ws + 173015040);
    float* SK   = (float*)(ws + 173539328);

    // weight transposes/converts to Bt[n][k] bf16
    tconv_kernel<<<dim3(1, 16, 16), 256, 0, stream>>>(WV, WVT, 1024, 64, 1024L*64, 64L*1024);
    tconv_kernel<<<dim3(1, 1, 1024), 256, 0, stream>>>(WO, WOT, 64, 16, 1024L, 1024L);
    tconv_kernel<<<dim3(64, 16, 1), 256, 0, stream>>>(W1, W1T, 1024, 4096, 0L, 0L);
    tconv_kernel<<<dim3(16, 64, 1), 256, 0, stream>>>(W2, W2T, 4096, 1024, 0L, 0L);

    // LN1 + q/k rank-1 projections + tanh/cos/sin
    ln_kernel<true><<<8192, 256, 0, stream>>>(x, ln1w, ln1b, Ybf, WQ, WK, CQ, SQ, CK, SK);

    // V = y @ Wv   (8192x1024x1024)
    gemm256<0><<<128, 512, 0, stream>>>(Ybf, WVT, Vbf, nullptr, nullptr, 8192, 1024, 1024, 4);

    // cumsum scan + heads
    scan_kernel<<<64, 64, 0, stream>>>(Vbf, CQ, SQ, CK, SK, Hbf);

    // x2 = x + heads @ Wo   (8192x1024x1024)
    gemm256<1><<<128, 512, 0, stream>>>(Hbf, WOT, X2, x, nullptr, 8192, 1024, 1024, 4);

    // LN2 (y2 reuses Ybf)
    ln_kernel<false><<<8192, 256, 0, stream>>>(X2, ln2w, ln2b, Ybf,
                                               nullptr, nullptr, nullptr, nullptr, nullptr, nullptr);

    // h1 = gelu(y2 @ W1 + b1)  (8192x4096x1024)
    gemm256<2><<<512, 512, 0, stream>>>(Ybf, W1T, H1, nullptr, b1, 8192, 4096, 1024, 16);

    // out = x2 + h1 @ W2 + b2  (8192x1024x4096)
    gemm256<3><<<128, 512, 0, stream>>>(H1, W2T, out, X2, b2, 8192, 1024, 4096, 4);
}

// Round 5
// 507.518 us; speedup vs baseline: 1.1349x; 1.1349x over previous
//
#include <hip/hip_runtime.h>
#include <hip/hip_bf16.h>
#include <stdint.h>

typedef unsigned short u16;
typedef __attribute__((ext_vector_type(4))) unsigned int u32x4;
typedef __attribute__((ext_vector_type(8))) __bf16 bfx8;
typedef __attribute__((ext_vector_type(4))) float f32x4;

#define PI_F 3.14159265358979323846f

__device__ __forceinline__ float bf2f(u16 u) {
    unsigned v = ((unsigned)u) << 16; float f; __builtin_memcpy(&f, &v, 4); return f;
}
__device__ __forceinline__ u16 f2bf(float f) {
    unsigned u; __builtin_memcpy(&u, &f, 4);
    unsigned r = (u + 0x7fffu + ((u >> 16) & 1u)) >> 16; return (u16)r;
}

// global -> LDS direct DMA, 16B per lane. LDS dest must be lane-linear.
__device__ __forceinline__ void glds16(const u16* g, const u16* l) {
    __builtin_amdgcn_global_load_lds(
        (const __attribute__((address_space(1))) unsigned int*)(unsigned long long)g,
        (__attribute__((address_space(3))) unsigned int*)(unsigned int)(unsigned long long)l,
        16, 0, 0);
}

// ---------------------------------------------------------------------------
// Generic tiled transpose + f32->bf16 convert:  out[c][r] = in[r][c], batched.
// ---------------------------------------------------------------------------
__global__ __launch_bounds__(256)
void tconv_kernel(const float* __restrict__ in, u16* __restrict__ out,
                  int R, int C, long inBatch, long outBatch)
{
    __shared__ float tile[64][65];
    const int tx = threadIdx.x & 63;
    const int ty = threadIdx.x >> 6;
    const int bc = blockIdx.x * 64;
    const int br = blockIdx.y * 64;
    const float* ip = in + (long)blockIdx.z * inBatch;
    u16* op = out + (long)blockIdx.z * outBatch;

    #pragma unroll
    for (int rr = ty; rr < 64; rr += 4) {
        int r = br + rr, c = bc + tx;
        tile[rr][tx] = (r < R && c < C) ? ip[(long)r * C + c] : 0.f;
    }
    __syncthreads();
    #pragma unroll
    for (int rr = ty; rr < 64; rr += 4) {
        int oc = bc + rr;
        int orr = br + tx;
        if (oc < C && orr < R)
            op[(long)oc * R + orr] = f2bf(tile[tx][rr]);
    }
}

// ---------------------------------------------------------------------------
// LayerNorm (+ optional rank-1 q/k projections + tanh/cos/sin).
// ---------------------------------------------------------------------------
template<bool DO_QK>
__global__ __launch_bounds__(256)
void ln_kernel(const float* __restrict__ X, const float* __restrict__ w,
               const float* __restrict__ b, u16* __restrict__ Ybf,
               const float* __restrict__ WQ, const float* __restrict__ WK,
               float* __restrict__ cqA, float* __restrict__ sqA,
               float* __restrict__ ckA, float* __restrict__ skA)
{
    __shared__ float yrow[1024];
    __shared__ float wsum[4], wsq[4];
    const int row = blockIdx.x;
    const int tid = threadIdx.x;
    const int lane = tid & 63;
    const int wv = tid >> 6;

    const float4 xv = ((const float4*)(X + (long)row * 1024))[tid];
    float s  = xv.x + xv.y + xv.z + xv.w;
    float sq = xv.x*xv.x + xv.y*xv.y + xv.z*xv.z + xv.w*xv.w;
    #pragma unroll
    for (int off = 32; off; off >>= 1) {
        s  += __shfl_down(s, off);
        sq += __shfl_down(sq, off);
    }
    if (lane == 0) { wsum[wv] = s; wsq[wv] = sq; }
    __syncthreads();
    const float ts = wsum[0] + wsum[1] + wsum[2] + wsum[3];
    const float tq = wsq[0] + wsq[1] + wsq[2] + wsq[3];
    const float mean = ts * (1.f / 1024.f);
    const float var  = tq * (1.f / 1024.f) - mean * mean;
    const float rstd = rsqrtf(var + 1e-5f);

    const float4 wv4 = ((const float4*)w)[tid];
    const float4 bv4 = ((const float4*)b)[tid];
    const float y0 = (xv.x - mean) * rstd * wv4.x + bv4.x;
    const float y1 = (xv.y - mean) * rstd * wv4.y + bv4.y;
    const float y2 = (xv.z - mean) * rstd * wv4.z + bv4.z;
    const float y3 = (xv.w - mean) * rstd * wv4.w + bv4.w;

    uint2 p;
    p.x = (unsigned)f2bf(y0) | ((unsigned)f2bf(y1) << 16);
    p.y = (unsigned)f2bf(y2) | ((unsigned)f2bf(y3) << 16);
    ((uint2*)(Ybf + (long)row * 1024))[tid] = p;

    if (DO_QK) {
        yrow[tid*4+0] = y0; yrow[tid*4+1] = y1;
        yrow[tid*4+2] = y2; yrow[tid*4+3] = y3;
        __syncthreads();
        #pragma unroll
        for (int i = 0; i < 4; ++i) {
            const int h = wv * 4 + i;
            const float* wqp = WQ + (long)h * 1024;
            const float* wkp = WK + (long)h * 1024;
            float dq = 0.f, dk = 0.f;
            #pragma unroll
            for (int j = 0; j < 16; ++j) {
                const float yv = yrow[lane + 64*j];
                dq = fmaf(yv, wqp[lane + 64*j], dq);
                dk = fmaf(yv, wkp[lane + 64*j], dk);
            }
            #pragma unroll
            for (int off = 32; off; off >>= 1) {
                dq += __shfl_down(dq, off);
                dk += __shfl_down(dk, off);
            }
            if (lane == 0) {
                const float aq = tanhf(dq) * (PI_F * 0.25f);
                const float ak = tanhf(dk) * (PI_F * 0.25f);
                float sv, cv;
                const long o = (long)h * 8192 + row;
                __sincosf(aq, &sv, &cv); cqA[o] = cv; sqA[o] = sv;
                __sincosf(ak, &sv, &cv); ckA[o] = cv; skA[o] = sv;
            }
        }
    }
}

// ---------------------------------------------------------------------------
// Fused cumsum scan + heads: one block (8 waves) per (b, head).
// Wave w owns T-chunk [w*256, w*256+256). Two-pass: chunk totals -> LDS
// prefix -> emit with carry. Lane = Dh column.
// ---------------------------------------------------------------------------
__global__ __launch_bounds__(512)
void scan_kernel(const u16* __restrict__ V,
                 const float* __restrict__ cqA, const float* __restrict__ sqA,
                 const float* __restrict__ ckA, const float* __restrict__ skA,
                 u16* __restrict__ H)
{
    __shared__ float totcV[8][64], totsV[8][64];
    __shared__ float totc[8], tots[8];
    const int b = blockIdx.x >> 4;
    const int h = blockIdx.x & 15;
    const int wv = threadIdx.x >> 6;
    const int lane = threadIdx.x & 63;
    const long rowbase = (long)b * 2048;
    const long qbase = (long)h * 8192 + rowbase;
    const int t0 = wv * 256;

    const u16* vp = V + (rowbase + t0) * 1024 + (long)h * 64 + lane;

    // pass 1: chunk totals
    float tc = 0.f, ts = 0.f, kc = 0.f, ks = 0.f;
    #pragma unroll 4
    for (int tt = 0; tt < 256; ++tt) {
        const float ck = ckA[qbase + t0 + tt];
        const float sk = skA[qbase + t0 + tt];
        const float vx = bf2f(vp[(long)tt * 1024]);
        tc = fmaf(ck, vx, tc); ts = fmaf(sk, vx, ts);
        kc += ck; ks += sk;
    }
    totcV[wv][lane] = tc; totsV[wv][lane] = ts;
    if (lane == 0) { totc[wv] = kc; tots[wv] = ks; }
    __syncthreads();

    float carC = 0.f, carS = 0.f, carKc = 0.f, carKs = 0.f;
    for (int w2 = 0; w2 < wv; ++w2) {
        carC += totcV[w2][lane]; carS += totsV[w2][lane];
        carKc += totc[w2]; carKs += tots[w2];
    }

    // pass 2: emit
    float csum = carC, ssum = carS, kcs = carKc, kss = carKs;
    u16* outp = H + (rowbase + t0) * 1024 + (long)h * 64 + lane;
    #pragma unroll 4
    for (int tt = 0; tt < 256; ++tt) {
        const long qo = qbase + t0 + tt;
        const float ck = ckA[qo], sk = skA[qo];
        const float cq = cqA[qo], sq2 = sqA[qo];
        const float vx = bf2f(vp[(long)tt * 1024]);
        csum = fmaf(ck, vx, csum); ssum = fmaf(sk, vx, ssum);
        kcs += ck; kss += sk;
        const float denom = cq * kcs + sq2 * kss + 1e-6f;
        const float hv = (cq * csum + sq2 * ssum) / denom;
        outp[(long)tt * 1024] = f2bf(hv);
    }
}

// ---------------------------------------------------------------------------
// Deep-pipelined bf16 MFMA GEMM:  C = A[M][K] * B^T (Bt [N][K]).
// BM=256, BN=256 (4 phases/K-tile) or 128 (2 phases), BK=64, 8 waves (2Mx4N).
// Per phase: {ds_read frag group | stage ONE 2-issue glds group for tile t+1 |
// raw s_barrier | lgkmcnt(0) | setprio(1) 16 MFMA setprio(0) | counted vmcnt |
// raw s_barrier}. Never vmcnt(0) in the loop; leads 2-4 phases.
// Stripe-mapped stage groups align with per-phase consumption:
//   A grp0 = rows {0-63,128-191} (mi0..3 of both wave-halves), grp1 = rest.
//   B(256) grp0 = rows {0-31,64-95,128-159,192-223} (n-half0), grp1 = rest.
// Chunk-rotation LDS swizzle: logical 16B chunk c of row r at phys (c+r%8)%8
// (0-conflict verified in rounds 2-4).
// EPI: 0 bf16 store; 1 f32 +res; 2 bf16 gelu(+bias); 3 f32 +res+bias.
// ---------------------------------------------------------------------------
template<int EPI, int BN>
__global__ __launch_bounds__(512, 2)
void gemm5(const u16* __restrict__ A, const u16* __restrict__ B,
           void* __restrict__ Cout, const float* __restrict__ res,
           const float* __restrict__ bias, int N, int K, int nx)
{
    constexpr int NFR = BN / 64;            // 4 (BN=256) or 2 (BN=128)
    constexpr int BSTR = BN * 64;           // B buffer stride in u16
    __shared__ u16 As[2 * 256 * 64];
    __shared__ u16 Bs[2 * BSTR];

    const int tid  = threadIdx.x;
    const int lane = tid & 63;
    const int wave = tid >> 6;
    const int wr = wave >> 2;
    const int wc = wave & 3;
    const int rr = lane & 15;
    const int kq = lane >> 4;

    const int L = blockIdx.x;
    const int xcd = L & 7;
    const int qq = L >> 3;
    const int brow = ((qq / nx) * 8 + xcd) * 256;
    const int bcol = (qq % nx) * BN;

    // staging thread map: v = row-slot (0..63), chp = phys chunk, clog = src chunk
    const int v = tid >> 3;
    const int chp = tid & 7;
    const int clog = (chp - (v & 7)) & 7;
    const u16* AgB = A + (long)(brow + v) * K + clog * 8;
    const int rowB = (BN == 256) ? (v + (v & 32)) : v;
    const u16* BgB = B + (long)(bcol + rowB) * K + clog * 8;
    const long K64 = (long)64 * K;

    // fragment read offsets (bytes)
    const int ph0 = ((kq + (rr & 7)) & 7) * 16;
    const int ph1 = ((kq + 4 + (rr & 7)) & 7) * 16;
    const int arb = rr * 128;
    const int aq0 = wr * 8192;
    const int aq1 = (2 + wr) * 8192;
    const int bq0 = (wc >> 1) * 8192 + (wc & 1) * 4096;   // also BN=128 base
    const int bq1 = (2 + (wc >> 1)) * 8192 + (wc & 1) * 4096;

    f32x4 acc[8][NFR];
    #pragma unroll
    for (int i = 0; i < 8; ++i)
        #pragma unroll
        for (int j = 0; j < NFR; ++j) acc[i][j] = (f32x4){0.f, 0.f, 0.f, 0.f};

    const int NT = K >> 6;
    const char* AsB = (const char*)As;
    const char* BsB = (const char*)Bs;

#define STAGE_A0(nb, kn) { glds16(AgB + (kn),             &As[(nb)*16384 + tid*8]); \
                           glds16(AgB + (kn) + 2*K64,     &As[(nb)*16384 + 4096 + tid*8]); }
#define STAGE_A1(nb, kn) { glds16(AgB + (kn) + K64,       &As[(nb)*16384 + 8192 + tid*8]); \
                           glds16(AgB + (kn) + 3*K64,     &As[(nb)*16384 + 12288 + tid*8]); }
#define STAGE_B0(nb, kn) { glds16(BgB + (kn),             &Bs[(nb)*16384 + tid*8]); \
                           glds16(BgB + (kn) + 2*K64,     &Bs[(nb)*16384 + 4096 + tid*8]); }
#define STAGE_B1(nb, kn) { glds16(BgB + (kn) + (K64>>1),  &Bs[(nb)*16384 + 8192 + tid*8]); \
                           glds16(BgB + (kn) + (K64>>1) + 2*K64, &Bs[(nb)*16384 + 12288 + tid*8]); }
#define STAGE_B128(nb, kn) { glds16(BgB + (kn),           &Bs[(nb)*8192 + tid*8]); \
                             glds16(BgB + (kn) + K64,     &Bs[(nb)*8192 + 4096 + tid*8]); }
#define BAR  asm volatile("s_barrier" ::: "memory")
#define LGKM0 asm volatile("s_waitcnt lgkmcnt(0)" ::: "memory")
#define SB __builtin_amdgcn_sched_barrier(0)

    // prologue: stage tile 0 fully into buf 0
    if constexpr (BN == 256) {
        STAGE_A0(0, 0); STAGE_B0(0, 0); STAGE_B1(0, 0); STAGE_A1(0, 0);
    } else {
        STAGE_A0(0, 0); STAGE_B128(0, 0); STAGE_A1(0, 0);
    }
    asm volatile("s_waitcnt vmcnt(0)" ::: "memory");
    BAR;

    for (int t = 0; t < NT; ++t) {
        const int buf = t & 1, nb = buf ^ 1;
        const long kn = (long)((t + 1 < NT) ? (t + 1) : 0) * 64;
        const char* Ap = AsB + buf * 32768;
        const char* Bp = BsB + buf * (BSTR * 2);

        if constexpr (BN == 256) {
            bfx8 a0[8], a1[8], b0[4], b1[4];
            // ---- p0: read A-g0 + B-g0; stage A-g0(t+1); MFMA Q0
            #pragma unroll
            for (int mi = 0; mi < 4; ++mi) {
                a0[mi*2+0] = *(const bfx8*)(Ap + aq0 + mi*2048 + arb + ph0);
                a0[mi*2+1] = *(const bfx8*)(Ap + aq0 + mi*2048 + arb + ph1);
            }
            #pragma unroll
            for (int nf = 0; nf < 2; ++nf) {
                b0[nf*2+0] = *(const bfx8*)(Bp + bq0 + nf*2048 + arb + ph0);
                b0[nf*2+1] = *(const bfx8*)(Bp + bq0 + nf*2048 + arb + ph1);
            }
            STAGE_A0(nb, kn);
            BAR; LGKM0; SB;
            __builtin_amdgcn_s_setprio(1);
            #pragma unroll
            for (int mi = 0; mi < 4; ++mi)
                #pragma unroll
                for (int nf = 0; nf < 2; ++nf) {
                    acc[mi][nf] = __builtin_amdgcn_mfma_f32_16x16x32_bf16(a0[mi*2+0], b0[nf*2+0], acc[mi][nf], 0, 0, 0);
                    acc[mi][nf] = __builtin_amdgcn_mfma_f32_16x16x32_bf16(a0[mi*2+1], b0[nf*2+1], acc[mi][nf], 0, 0, 0);
                }
            __builtin_amdgcn_s_setprio(0); SB;
            asm volatile("s_waitcnt vmcnt(4)" ::: "memory");
            BAR;
            // ---- p1: read B-g1; stage B-g0(t+1); MFMA Q1
            #pragma unroll
            for (int nf = 0; nf < 2; ++nf) {
                b1[nf*2+0] = *(const bfx8*)(Bp + bq1 + nf*2048 + arb + ph0);
                b1[nf*2+1] = *(const bfx8*)(Bp + bq1 + nf*2048 + arb + ph1);
            }
            STAGE_B0(nb, kn);
            BAR; LGKM0; SB;
            __builtin_amdgcn_s_setprio(1);
            #pragma unroll
            for (int mi = 0; mi < 4; ++mi)
                #pragma unroll
                for (int nf = 0; nf < 2; ++nf) {
                    acc[mi][2+nf] = __builtin_amdgcn_mfma_f32_16x16x32_bf16(a0[mi*2+0], b1[nf*2+0], acc[mi][2+nf], 0, 0, 0);
                    acc[mi][2+nf] = __builtin_amdgcn_mfma_f32_16x16x32_bf16(a0[mi*2+1], b1[nf*2+1], acc[mi][2+nf], 0, 0, 0);
                }
            __builtin_amdgcn_s_setprio(0); SB;
            asm volatile("s_waitcnt vmcnt(4)" ::: "memory");
            BAR;
            // ---- p2: read A-g1; stage B-g1(t+1); MFMA Q2
            #pragma unroll
            for (int mi = 0; mi < 4; ++mi) {
                a1[mi*2+0] = *(const bfx8*)(Ap + aq1 + mi*2048 + arb + ph0);
                a1[mi*2+1] = *(const bfx8*)(Ap + aq1 + mi*2048 + arb + ph1);
            }
            STAGE_B1(nb, kn);
            BAR; LGKM0; SB;
            __builtin_amdgcn_s_setprio(1);
            #pragma unroll
            for (int mi = 0; mi < 4; ++mi)
                #pragma unroll
                for (int nf = 0; nf < 2; ++nf) {
                    acc[4+mi][2+nf] = __builtin_amdgcn_mfma_f32_16x16x32_bf16(a1[mi*2+0], b1[nf*2+0], acc[4+mi][2+nf], 0, 0, 0);
                    acc[4+mi][2+nf] = __builtin_amdgcn_mfma_f32_16x16x32_bf16(a1[mi*2+1], b1[nf*2+1], acc[4+mi][2+nf], 0, 0, 0);
                }
            __builtin_amdgcn_s_setprio(0); SB;
            BAR;
            // ---- p3: no reads; stage A-g1(t+1); MFMA Q3
            STAGE_A1(nb, kn);
            BAR; SB;
            __builtin_amdgcn_s_setprio(1);
            #pragma unroll
            for (int mi = 0; mi < 4; ++mi)
                #pragma unroll
                for (int nf = 0; nf < 2; ++nf) {
                    acc[4+mi][nf] = __builtin_amdgcn_mfma_f32_16x16x32_bf16(a1[mi*2+0], b0[nf*2+0], acc[4+mi][nf], 0, 0, 0);
                    acc[4+mi][nf] = __builtin_amdgcn_mfma_f32_16x16x32_bf16(a1[mi*2+1], b0[nf*2+1], acc[4+mi][nf], 0, 0, 0);
                }
            __builtin_amdgcn_s_setprio(0); SB;
            asm volatile("s_waitcnt vmcnt(4)" ::: "memory");
            BAR;
        } else {
            bfx8 a0[8], a1[8], bb[4];
            // ---- p0: read A-g0 + B; stage A-g0(t+1) + B(t+1); MFMA m-half0
            #pragma unroll
            for (int mi = 0; mi < 4; ++mi) {
                a0[mi*2+0] = *(const bfx8*)(Ap + aq0 + mi*2048 + arb + ph0);
                a0[mi*2+1] = *(const bfx8*)(Ap + aq0 + mi*2048 + arb + ph1);
            }
            #pragma unroll
            for (int nf = 0; nf < 2; ++nf) {
                bb[nf*2+0] = *(const bfx8*)(Bp + bq0 + nf*2048 + arb + ph0);
                bb[nf*2+1] = *(const bfx8*)(Bp + bq0 + nf*2048 + arb + ph1);
            }
            STAGE_A0(nb, kn); STAGE_B128(nb, kn);
            BAR; LGKM0; SB;
            __builtin_amdgcn_s_setprio(1);
            #pragma unroll
            for (int mi = 0; mi < 4; ++mi)
                #pragma unroll
                for (int nf = 0; nf < 2; ++nf) {
                    acc[mi][nf] = __builtin_amdgcn_mfma_f32_16x16x32_bf16(a0[mi*2+0], bb[nf*2+0], acc[mi][nf], 0, 0, 0);
                    acc[mi][nf] = __builtin_amdgcn_mfma_f32_16x16x32_bf16(a0[mi*2+1], bb[nf*2+1], acc[mi][nf], 0, 0, 0);
                }
            __builtin_amdgcn_s_setprio(0); SB;
            asm volatile("s_waitcnt vmcnt(4)" ::: "memory");
            BAR;
            // ---- p1: read A-g1; stage A-g1(t+1); MFMA m-half1
            #pragma unroll
            for (int mi = 0; mi < 4; ++mi) {
                a1[mi*2+0] = *(const bfx8*)(Ap + aq1 + mi*2048 + arb + ph0);
                a1[mi*2+1] = *(const bfx8*)(Ap + aq1 + mi*2048 + arb + ph1);
            }
            STAGE_A1(nb, kn);
            BAR; LGKM0; SB;
            __builtin_amdgcn_s_setprio(1);
            #pragma unroll
            for (int mi = 0; mi < 4; ++mi)
                #pragma unroll
                for (int nf = 0; nf < 2; ++nf) {
                    acc[4+mi][nf] = __builtin_amdgcn_mfma_f32_16x16x32_bf16(a1[mi*2+0], bb[nf*2+0], acc[4+mi][nf], 0, 0, 0);
                    acc[4+mi][nf] = __builtin_amdgcn_mfma_f32_16x16x32_bf16(a1[mi*2+1], bb[nf*2+1], acc[4+mi][nf], 0, 0, 0);
                }
            __builtin_amdgcn_s_setprio(0); SB;
            asm volatile("s_waitcnt vmcnt(2)" ::: "memory");
            BAR;
        }
    }
#undef STAGE_A0
#undef STAGE_A1
#undef STAGE_B0
#undef STAGE_B1
#undef STAGE_B128
#undef BAR
#undef LGKM0
#undef SB

    // epilogue
    const int crow0 = brow + wr * 128 + kq * 4;
    const int ccol0 = bcol + wc * (BN / 4) + rr;
    #pragma unroll
    for (int mi = 0; mi < 8; ++mi) {
        #pragma unroll
        for (int ni = 0; ni < NFR; ++ni) {
            const int col = ccol0 + ni * 16;
            #pragma unroll
            for (int r = 0; r < 4; ++r) {
                const int row = crow0 + mi * 16 + r;
                const long idx = (long)row * N + col;
                const float vvv = acc[mi][ni][r];
                if (EPI == 0) {
                    ((u16*)Cout)[idx] = f2bf(vvv);
                } else if (EPI == 1) {
                    ((float*)Cout)[idx] = vvv + res[idx];
                } else if (EPI == 2) {
                    const float hh = vvv + bias[col];
                    const float z = 0.7978845608028654f * (hh + 0.044715f * hh * hh * hh);
                    const float e = __expf(2.f * z);
                    const float th = 1.f - 2.f / (e + 1.f);
                    ((u16*)Cout)[idx] = f2bf(0.5f * hh * (1.f + th));
                } else {
                    ((float*)Cout)[idx] = vvv + res[idx] + bias[col];
                }
            }
        }
    }
}

// ---------------------------------------------------------------------------
extern "C" void kernel_launch(void* const* d_in, const int* in_sizes, int n_in,
                              void* d_out, int out_size, void* d_ws, size_t ws_size,
                              hipStream_t stream)
{
    (void)in_sizes; (void)n_in; (void)out_size; (void)ws_size;
    const float* x    = (const float*)d_in[0];
    const float* WQ   = (const float*)d_in[1];
    const float* WK   = (const float*)d_in[2];
    const float* WV   = (const float*)d_in[3];
    const float* WO   = (const float*)d_in[4];
    const float* ln1w = (const float*)d_in[5];
    const float* ln1b = (const float*)d_in[6];
    const float* ln2w = (const float*)d_in[7];
    const float* ln2b = (const float*)d_in[8];
    const float* W1   = (const float*)d_in[9];
    const float* b1   = (const float*)d_in[10];
    const float* W2   = (const float*)d_in[11];
    const float* b2   = (const float*)d_in[12];
    float* out = (float*)d_out;

    char* ws = (char*)d_ws;
    u16*   Ybf  = (u16*)(ws + 0);                    // 16 MB (reused as y2)
    u16*   Vbf  = (u16*)(ws + 16777216);             // 16 MB
    u16*   Hbf  = (u16*)(ws + 33554432);             // 16 MB
    float* X2   = (float*)(ws + 50331648);           // 32 MB
    u16*   H1   = (u16*)(ws + 83886080);             // 64 MB
    u16*   WVT  = (u16*)(ws + 150994944);            //  2 MB
    u16*   WOT  = (u16*)(ws + 153092096);            //  2 MB
    u16*   W1T  = (u16*)(ws + 155189248);            //  8 MB
    u16*   W2T  = (u16*)(ws + 163577856);            //  8 MB
    float* CQ   = (float*)(ws + 171966464);
    float* SQ   = (float*)(ws + 172490752);
    float* CK   = (float*)(ws + 173015040);
    float* SK   = (float*)(ws + 173539328);

    // weight transposes/converts to Bt[n][k] bf16
    tconv_kernel<<<dim3(1, 16, 16), 256, 0, stream>>>(WV, WVT, 1024, 64, 1024L*64, 64L*1024);
    tconv_kernel<<<dim3(1, 1, 1024), 256, 0, stream>>>(WO, WOT, 64, 16, 1024L, 1024L);
    tconv_kernel<<<dim3(64, 16, 1), 256, 0, stream>>>(W1, W1T, 1024, 4096, 0L, 0L);
    tconv_kernel<<<dim3(16, 64, 1), 256, 0, stream>>>(W2, W2T, 4096, 1024, 0L, 0L);

    // LN1 + q/k rank-1 projections + tanh/cos/sin
    ln_kernel<true><<<8192, 256, 0, stream>>>(x, ln1w, ln1b, Ybf, WQ, WK, CQ, SQ, CK, SK);

    // V = y @ Wv   (8192x1024x1024)
    gemm5<0, 128><<<256, 512, 0, stream>>>(Ybf, WVT, Vbf, nullptr, nullptr, 1024, 1024, 8);

    // cumsum scan + heads
    scan_kernel<<<64, 512, 0, stream>>>(Vbf, CQ, SQ, CK, SK, Hbf);

    // x2 = x + heads @ Wo   (8192x1024x1024)
    gemm5<1, 128><<<256, 512, 0, stream>>>(Hbf, WOT, X2, x, nullptr, 1024, 1024, 8);

    // LN2 (y2 reuses Ybf)
    ln_kernel<false><<<8192, 256, 0, stream>>>(X2, ln2w, ln2b, Ybf,
                                               nullptr, nullptr, nullptr, nullptr, nullptr, nullptr);

    // h1 = gelu(y2 @ W1 + b1)  (8192x4096x1024)
    gemm5<2, 256><<<512, 512, 0, stream>>>(Ybf, W1T, H1, nullptr, b1, 4096, 1024, 16);

    // out = x2 + h1 @ W2 + b2  (8192x1024x4096)
    gemm5<3, 128><<<256, 512, 0, stream>>>(H1, W2T, out, X2, b2, 1024, 4096, 8);
}